// Round 6
// baseline (108.859 us; speedup 1.0000x reference)
//
#include <hip/hip_runtime.h>

typedef __bf16 bf16_t;
typedef bf16_t bf16x4 __attribute__((ext_vector_type(4)));
typedef bf16_t bf16x8 __attribute__((ext_vector_type(8)));
typedef float f32x4 __attribute__((ext_vector_type(4)));
typedef float f32x16 __attribute__((ext_vector_type(16)));

namespace {
constexpr int kNH  = 16;
constexpr int kHD  = 64;
constexpr int kHID = kNH * kHD;   // 1024
constexpr int kSQ  = 2048;
constexpr int kKP  = 72;          // Q LDS pitch (bf16)
constexpr int kOmPitch = 68;      // epilogue float pitch
constexpr int kSmBytes = 71680;
constexpr int kKbElems = kNH * kSQ * kHD;  // 2,097,152 bf16 = 4 MB
}

// ---------------------------------------------------------------------------
// Prep pass (unchanged): head-major bf16 K pack + kappa-order V gather.
// ---------------------------------------------------------------------------
__global__ __launch_bounds__(256)
void prep_kernel(const float* __restrict__ Kg, const float* __restrict__ Vg,
                 bf16_t* __restrict__ Kb, bf16_t* __restrict__ Vb) {
  const int bid = blockIdx.x;
  const int tid = threadIdx.x;
  if (bid < 1024) {
    const int o    = (bid * 256 + tid) * 8;    // bf16 out index in Kb
    const int head = o >> 17;                  // 131072 = 2048*64
    const int t    = (o >> 6) & 2047;
    const int d0   = o & 63;
    const float4 f0 = *(const float4*)(Kg + (size_t)t * kHID + head * kHD + d0);
    const float4 f1 = *(const float4*)(Kg + (size_t)t * kHID + head * kHD + d0 + 4);
    bf16x8 hk;
    hk[0] = (bf16_t)f0.x; hk[1] = (bf16_t)f0.y; hk[2] = (bf16_t)f0.z; hk[3] = (bf16_t)f0.w;
    hk[4] = (bf16_t)f1.x; hk[5] = (bf16_t)f1.y; hk[6] = (bf16_t)f1.z; hk[7] = (bf16_t)f1.w;
    *(bf16x8*)(Kb + o) = hk;
  } else {
    const int vb   = bid - 1024;               // one (head, tile) per block
    const int head = vb >> 6;
    const int tile = vb & 63;
    const int lane = tid >> 2;                 // 0..63
    const int hh   = lane >> 5;
    const int m31  = lane & 31;
    const int q    = tid & 3;
    const int db   = q >> 1, tp = q & 1;
    const int tb   = tile * 32 + 4 * hh + 16 * tp;
    const int d    = m31 + 32 * db;
    const float* src = Vg + (size_t)tb * kHID + head * kHD + d;
    bf16x8 hv;
    #pragma unroll
    for (int j = 0; j < 8; ++j)
      hv[j] = (bf16_t)src[(size_t)((j & 3) + 8 * (j >> 2)) * kHID];
    *(bf16x8*)(Vb + ((size_t)(head * 64 + tile) * 64 + lane) * 32 + (db * 16 + tp * 8)) = hv;
  }
}

// R16 — DIAGNOSTIC ROUND. Identical to R14/R4 (zero-LDS single-buffer main
// loop, best clean structure) except the whole per-block computation runs
// rep=2 times in ONE dispatch (idempotent: O rewritten identically). This
// forces the fattn dispatch to ~80+us so it finally lands in rocprof's top-5
// with full counters (5 rounds of fills at ~44-46us have hidden it). The +40us
// total regression is the price of the measurement; revert rep=1 next round.
__global__ __launch_bounds__(512, 2)
void fattn_kernel(const float* __restrict__ Qg, const bf16_t* __restrict__ Kb,
                  const bf16_t* __restrict__ Vb, float* __restrict__ Og) {
  __shared__ __align__(16) unsigned char smraw[kSmBytes];
  bf16_t* sm = (bf16_t*)smraw;
  bf16_t* qs = sm;                     // Q tile 64 x kKP (epilogue reuses LDS)

  const int bid  = blockIdx.x;
  const int head = bid & (kNH - 1);
  const int ip   = bid >> 4;          // 0..15: pair (31-ip, ip)

  const int tid  = threadIdx.x;
  const int wave = tid >> 6;          // 0..7: key-group, tiles jt == wave (mod 8)
  const int lane = tid & 63;
  const int h    = lane >> 5;
  const int m31  = lane & 31;

  const float kQScale = 0.125f * 1.44269504088896340736f;  // 1/sqrt(64)*log2(e)

  // per-lane fragment base pointers into the packed bf16 buffers
  const bf16_t* kfb = Kb + (size_t)head * (kSQ * kHD) + (size_t)m31 * kHD + 8 * h;
  const bf16_t* vfb = Vb + ((size_t)head * 64 * 64 + lane) * 32;

  #pragma unroll 1
  for (int rep = 0; rep < 2; ++rep) {
  for (int halfq = 0; halfq < 2; ++halfq) {
    const int mblk = halfq ? ip : (31 - ip);   // big q-tile first
    const int m0   = mblk * 64;
    const int mtk  = 2 * mblk + 1;             // last 32-key tile index

    // ---- stage Q tile (64 rows); barrier covers prior epilogue's LDS reads ----
    __syncthreads();
    #pragma unroll
    for (int i = 0; i < 2; ++i) {
      const int idx = tid + 512 * i;          // 1024 float4s
      const int row = idx >> 4;
      const int c4  = (idx & 15) * 4;
      const float4 f = *(const float4*)(Qg + (size_t)(m0 + row) * kHID + head * kHD + c4);
      bf16x4 qv;
      qv[0] = (bf16_t)(f.x * kQScale); qv[1] = (bf16_t)(f.y * kQScale);
      qv[2] = (bf16_t)(f.z * kQScale); qv[3] = (bf16_t)(f.w * kQScale);
      *(bf16x4*)(qs + row * kKP + c4) = qv;
    }
    __syncthreads();

    // ---- hoist Q fragments: loop-invariant, 8 x bf16x8 = 32 VGPRs ----
    bf16x8 qf00 = *(const bf16x8*)(qs + m31 * kKP +  0 + 8 * h);
    bf16x8 qf01 = *(const bf16x8*)(qs + m31 * kKP + 16 + 8 * h);
    bf16x8 qf02 = *(const bf16x8*)(qs + m31 * kKP + 32 + 8 * h);
    bf16x8 qf03 = *(const bf16x8*)(qs + m31 * kKP + 48 + 8 * h);
    bf16x8 qf10 = *(const bf16x8*)(qs + (32 + m31) * kKP +  0 + 8 * h);
    bf16x8 qf11 = *(const bf16x8*)(qs + (32 + m31) * kKP + 16 + 8 * h);
    bf16x8 qf12 = *(const bf16x8*)(qs + (32 + m31) * kKP + 32 + 8 * h);
    bf16x8 qf13 = *(const bf16x8*)(qs + (32 + m31) * kKP + 48 + 8 * h);

    // O^T accumulators; l partials per q-half
    f32x16 Oa00, Oa10, Oa01, Oa11;
    #pragma unroll
    for (int r = 0; r < 16; ++r) { Oa00[r] = 0.f; Oa10[r] = 0.f; Oa01[r] = 0.f; Oa11[r] = 0.f; }
    float lacc0 = 0.f, lacc1 = 0.f;

    // ---- single-buffered zero-LDS main loop ----
    bf16x8 k0, k1, k2, k3, v0, v1, v2, v3;
    int jt = wave;
    if (jt <= mtk) {
      const bf16_t* kp = kfb + (size_t)jt * 2048;
      k0 = *(const bf16x8*)(kp);      k1 = *(const bf16x8*)(kp + 16);
      k2 = *(const bf16x8*)(kp + 32); k3 = *(const bf16x8*)(kp + 48);
      const bf16_t* vp = vfb + (size_t)jt * 2048;
      v0 = *(const bf16x8*)(vp);      v1 = *(const bf16x8*)(vp + 8);
      v2 = *(const bf16x8*)(vp + 16); v3 = *(const bf16x8*)(vp + 24);
    }
    for (; jt <= mtk; jt += 8) {
      const int kv0  = jt * 32;
      const bool do0 = (kv0 <= m0);   // half0 live unless tile above diagonal

      // --- QK^T for both q-halves (K frags die here) ---
      f32x16 c0, c1;
      if (do0) {
        #pragma unroll
        for (int r = 0; r < 16; ++r) c0[r] = 0.f;
        c0 = __builtin_amdgcn_mfma_f32_32x32x16_bf16(k0, qf00, c0, 0, 0, 0);
        c0 = __builtin_amdgcn_mfma_f32_32x32x16_bf16(k1, qf01, c0, 0, 0, 0);
        c0 = __builtin_amdgcn_mfma_f32_32x32x16_bf16(k2, qf02, c0, 0, 0, 0);
        c0 = __builtin_amdgcn_mfma_f32_32x32x16_bf16(k3, qf03, c0, 0, 0, 0);
      }
      #pragma unroll
      for (int r = 0; r < 16; ++r) c1[r] = 0.f;
      c1 = __builtin_amdgcn_mfma_f32_32x32x16_bf16(k0, qf10, c1, 0, 0, 0);
      c1 = __builtin_amdgcn_mfma_f32_32x32x16_bf16(k1, qf11, c1, 0, 0, 0);
      c1 = __builtin_amdgcn_mfma_f32_32x32x16_bf16(k2, qf12, c1, 0, 0, 0);
      c1 = __builtin_amdgcn_mfma_f32_32x32x16_bf16(k3, qf13, c1, 0, 0, 0);

      // --- prefetch next K into the same regs (covers softmax+PV below) ---
      if (jt + 8 <= mtk) {
        const bf16_t* kp = kfb + (size_t)(jt + 8) * 2048;
        k0 = *(const bf16x8*)(kp);      k1 = *(const bf16x8*)(kp + 16);
        k2 = *(const bf16x8*)(kp + 32); k3 = *(const bf16x8*)(kp + 48);
      }

      // --- q-half 0: softmax + PV ---
      if (do0) {
        float p[16];
        if (kv0 == m0) {   // diagonal subtile
          #pragma unroll
          for (int r = 0; r < 16; ++r) {
            const int kr = (r & 3) + 8 * (r >> 2) + 4 * h;
            const float e = __builtin_amdgcn_exp2f(c0[r]);
            p[r] = (kr <= m31) ? e : 0.f;
            lacc0 += p[r];
          }
        } else {
          #pragma unroll
          for (int r = 0; r < 16; ++r) { p[r] = __builtin_amdgcn_exp2f(c0[r]); lacc0 += p[r]; }
        }
        bf16x8 pb0, pb1;
        #pragma unroll
        for (int j = 0; j < 8; ++j) { pb0[j] = (bf16_t)p[j]; pb1[j] = (bf16_t)p[8 + j]; }
        Oa00 = __builtin_amdgcn_mfma_f32_32x32x16_bf16(v0, pb0, Oa00, 0, 0, 0);
        Oa10 = __builtin_amdgcn_mfma_f32_32x32x16_bf16(v2, pb0, Oa10, 0, 0, 0);
        Oa00 = __builtin_amdgcn_mfma_f32_32x32x16_bf16(v1, pb1, Oa00, 0, 0, 0);
        Oa10 = __builtin_amdgcn_mfma_f32_32x32x16_bf16(v3, pb1, Oa10, 0, 0, 0);
      }

      // --- q-half 1: softmax + PV (V frags die here) ---
      {
        float p[16];
        if (kv0 == m0 + 32) {   // diagonal subtile
          #pragma unroll
          for (int r = 0; r < 16; ++r) {
            const int kr = (r & 3) + 8 * (r >> 2) + 4 * h;
            const float e = __builtin_amdgcn_exp2f(c1[r]);
            p[r] = (kr <= m31) ? e : 0.f;
            lacc1 += p[r];
          }
        } else {
          #pragma unroll
          for (int r = 0; r < 16; ++r) { p[r] = __builtin_amdgcn_exp2f(c1[r]); lacc1 += p[r]; }
        }
        bf16x8 pb0, pb1;
        #pragma unroll
        for (int j = 0; j < 8; ++j) { pb0[j] = (bf16_t)p[j]; pb1[j] = (bf16_t)p[8 + j]; }
        Oa01 = __builtin_amdgcn_mfma_f32_32x32x16_bf16(v0, pb0, Oa01, 0, 0, 0);
        Oa11 = __builtin_amdgcn_mfma_f32_32x32x16_bf16(v2, pb0, Oa11, 0, 0, 0);
        Oa01 = __builtin_amdgcn_mfma_f32_32x32x16_bf16(v1, pb1, Oa01, 0, 0, 0);
        Oa11 = __builtin_amdgcn_mfma_f32_32x32x16_bf16(v3, pb1, Oa11, 0, 0, 0);
      }

      // --- prefetch next V into the same regs (covers next tile's QK^T) ---
      if (jt + 8 <= mtk) {
        const bf16_t* vp = vfb + (size_t)(jt + 8) * 2048;
        v0 = *(const bf16x8*)(vp);      v1 = *(const bf16x8*)(vp + 8);
        v2 = *(const bf16x8*)(vp + 16); v3 = *(const bf16x8*)(vp + 24);
      }
    }

    // ---- epilogue: two passes (one per q-half), 8-way additive merge via LDS ----
    float* fv   = (float*)smraw;
    float* Om   = fv + wave * 32 * kOmPitch;   // per-wave 32 rows x 68
    float* larr = fv + 8 * 32 * kOmPitch;      // 8 waves x 64 l-partials

    #pragma unroll
    for (int qh = 0; qh < 2; ++qh) {
      __syncthreads();   // pass0: main-loop LDS dead; pass1: pass0 reads done
      {
        const f32x16& A0 = qh ? Oa01 : Oa00;   // d 0..31
        const f32x16& A1 = qh ? Oa11 : Oa10;   // d 32..63
        #pragma unroll
        for (int q = 0; q < 4; ++q) {
          f32x4 w0, w1;
          #pragma unroll
          for (int e = 0; e < 4; ++e) { w0[e] = A0[4 * q + e]; w1[e] = A1[4 * q + e]; }
          *(f32x4*)(Om + (size_t)m31 * kOmPitch + 8 * q + 4 * h)      = w0;
          *(f32x4*)(Om + (size_t)m31 * kOmPitch + 32 + 8 * q + 4 * h) = w1;
        }
        larr[wave * 64 + lane] = qh ? lacc1 : lacc0;
      }
      __syncthreads();
      {
        const int row = tid >> 4;             // 512 float4s: 32 rows x 16 cols
        const int c4  = (tid & 15) * 4;
        float l = 0.f;
        #pragma unroll
        for (int w = 0; w < 8; ++w)
          l += larr[w * 64 + row] + larr[w * 64 + 32 + row];
        const float inv = 1.f / l;
        f32x4 o;
        #pragma unroll
        for (int e = 0; e < 4; ++e) o[e] = 0.f;
        #pragma unroll
        for (int w = 0; w < 8; ++w) {
          const f32x4 a = *(const f32x4*)(fv + w * 32 * kOmPitch + (size_t)row * kOmPitch + c4);
          #pragma unroll
          for (int e = 0; e < 4; ++e) o[e] += a[e];
        }
        #pragma unroll
        for (int e = 0; e < 4; ++e) o[e] *= inv;
        *(f32x4*)(Og + (size_t)(m0 + 32 * qh + row) * kHID + head * kHD + c4) = o;
      }
    }
  }
  }  // rep
}

extern "C" void kernel_launch(void* const* d_in, const int* in_sizes, int n_in,
                              void* d_out, int out_size, void* d_ws, size_t ws_size,
                              hipStream_t stream) {
  (void)in_sizes; (void)n_in; (void)ws_size; (void)out_size;
  const float* Q = (const float*)d_in[0];
  const float* K = (const float*)d_in[1];
  const float* V = (const float*)d_in[2];
  float* O = (float*)d_out;
  bf16_t* Kb = (bf16_t*)d_ws;            // 4 MB: [head][t][d] bf16
  bf16_t* Vb = Kb + kKbElems;            // 4 MB: pre-gathered kappa order
  hipLaunchKernelGGL(prep_kernel, dim3(2048), dim3(256), 0, stream, K, V, Kb, Vb);
  dim3 grid(256);    // 16 heads x 16 q-tile PAIRS (31-ip, ip)
  dim3 block(512);   // 8 waves; rep=2 DIAGNOSTIC (idempotent double execution)
  hipLaunchKernelGGL(fattn_kernel, grid, block, 0, stream, Q, Kb, Vb, O);
}

// Round 7
// 92.596 us; speedup vs baseline: 1.1756x; 1.1756x over previous
//
#include <hip/hip_runtime.h>

typedef __bf16 bf16_t;
typedef bf16_t bf16x4 __attribute__((ext_vector_type(4)));
typedef bf16_t bf16x8 __attribute__((ext_vector_type(8)));
typedef float f32x4 __attribute__((ext_vector_type(4)));
typedef float f32x16 __attribute__((ext_vector_type(16)));

namespace {
constexpr int kNH  = 16;
constexpr int kHD  = 64;
constexpr int kHID = kNH * kHD;   // 1024
constexpr int kSQ  = 2048;
constexpr int kKP  = 72;          // Q LDS pitch (bf16)
constexpr int kOmPitch = 68;      // epilogue float pitch
constexpr int kSmBytes = 71680;
constexpr int kKbElems = kNH * kSQ * kHD;  // 2,097,152 bf16 = 4 MB
}

// ---------------------------------------------------------------------------
// Prep pass, R17: R6's budget reconciliation showed prep ~20-24us (the V-half's
// 2M scattered scalar 4B loads at 4KB stride), dwarfing fattn's ~21us. V-half
// rebuilt as a coalesced LDS transpose: float4-stream the 32x64 f32 subtile ->
// bf16 LDS tile (4KB) -> barrier -> kappa-order gather from LDS (2-way bank
// aliasing = free) -> identical Vb bytes. All global reads now streaming.
// K-half unchanged (already coalesced).
// ---------------------------------------------------------------------------
__global__ __launch_bounds__(256)
void prep_kernel(const float* __restrict__ Kg, const float* __restrict__ Vg,
                 bf16_t* __restrict__ Kb, bf16_t* __restrict__ Vb) {
  __shared__ bf16_t ls[32][64];              // V subtile, bf16 (4 KB)
  const int bid = blockIdx.x;
  const int tid = threadIdx.x;
  if (bid < 1024) {
    const int o    = (bid * 256 + tid) * 8;    // bf16 out index in Kb
    const int head = o >> 17;                  // 131072 = 2048*64
    const int t    = (o >> 6) & 2047;
    const int d0   = o & 63;
    const float4 f0 = *(const float4*)(Kg + (size_t)t * kHID + head * kHD + d0);
    const float4 f1 = *(const float4*)(Kg + (size_t)t * kHID + head * kHD + d0 + 4);
    bf16x8 hk;
    hk[0] = (bf16_t)f0.x; hk[1] = (bf16_t)f0.y; hk[2] = (bf16_t)f0.z; hk[3] = (bf16_t)f0.w;
    hk[4] = (bf16_t)f1.x; hk[5] = (bf16_t)f1.y; hk[6] = (bf16_t)f1.z; hk[7] = (bf16_t)f1.w;
    *(bf16x8*)(Kb + o) = hk;
  } else {
    const int vb   = bid - 1024;               // one (head, tile) per block
    const int head = vb >> 6;
    const int tile = vb & 63;
    // stage: 32 rows x 64 cols, fully-coalesced float4 reads, cvt once
    #pragma unroll
    for (int s = 0; s < 2; ++s) {
      const int idx = tid + 256 * s;           // 512 float4s
      const int row = idx >> 4;
      const int c4  = (idx & 15) * 4;
      const float4 f =
          *(const float4*)(Vg + (size_t)(tile * 32 + row) * kHID + head * kHD + c4);
      bf16x4 hv4;
      hv4[0] = (bf16_t)f.x; hv4[1] = (bf16_t)f.y;
      hv4[2] = (bf16_t)f.z; hv4[3] = (bf16_t)f.w;
      *(bf16x4*)(&ls[row][c4]) = hv4;
    }
    __syncthreads();
    // kappa-order gather from LDS; write identical bytes to Vb
    const int lane = tid >> 2;                 // 0..63
    const int hh   = lane >> 5;
    const int m31  = lane & 31;
    const int q    = tid & 3;
    const int db   = q >> 1, tp = q & 1;
    bf16x8 hv;
    #pragma unroll
    for (int j = 0; j < 8; ++j)
      hv[j] = ls[4 * hh + 16 * tp + (j & 3) + 8 * (j >> 2)][m31 + 32 * db];
    *(bf16x8*)(Vb + ((size_t)(head * 64 + tile) * 64 + lane) * 32 + (db * 16 + tp * 8)) = hv;
  }
}

// fattn: R14/R4 structure exactly (rep reverted to 1). Zero-LDS single-buffer
// main loop; ~21us cold / ~16us hot per R6's rep-delta measurement.
__global__ __launch_bounds__(512, 2)
void fattn_kernel(const float* __restrict__ Qg, const bf16_t* __restrict__ Kb,
                  const bf16_t* __restrict__ Vb, float* __restrict__ Og) {
  __shared__ __align__(16) unsigned char smraw[kSmBytes];
  bf16_t* sm = (bf16_t*)smraw;
  bf16_t* qs = sm;                     // Q tile 64 x kKP (epilogue reuses LDS)

  const int bid  = blockIdx.x;
  const int head = bid & (kNH - 1);
  const int ip   = bid >> 4;          // 0..15: pair (31-ip, ip)

  const int tid  = threadIdx.x;
  const int wave = tid >> 6;          // 0..7: key-group, tiles jt == wave (mod 8)
  const int lane = tid & 63;
  const int h    = lane >> 5;
  const int m31  = lane & 31;

  const float kQScale = 0.125f * 1.44269504088896340736f;  // 1/sqrt(64)*log2(e)

  // per-lane fragment base pointers into the packed bf16 buffers
  const bf16_t* kfb = Kb + (size_t)head * (kSQ * kHD) + (size_t)m31 * kHD + 8 * h;
  const bf16_t* vfb = Vb + ((size_t)head * 64 * 64 + lane) * 32;

  for (int halfq = 0; halfq < 2; ++halfq) {
    const int mblk = halfq ? ip : (31 - ip);   // big q-tile first
    const int m0   = mblk * 64;
    const int mtk  = 2 * mblk + 1;             // last 32-key tile index

    // ---- stage Q tile (64 rows); barrier covers prior epilogue's LDS reads ----
    __syncthreads();
    #pragma unroll
    for (int i = 0; i < 2; ++i) {
      const int idx = tid + 512 * i;          // 1024 float4s
      const int row = idx >> 4;
      const int c4  = (idx & 15) * 4;
      const float4 f = *(const float4*)(Qg + (size_t)(m0 + row) * kHID + head * kHD + c4);
      bf16x4 qv;
      qv[0] = (bf16_t)(f.x * kQScale); qv[1] = (bf16_t)(f.y * kQScale);
      qv[2] = (bf16_t)(f.z * kQScale); qv[3] = (bf16_t)(f.w * kQScale);
      *(bf16x4*)(qs + row * kKP + c4) = qv;
    }
    __syncthreads();

    // ---- hoist Q fragments: loop-invariant, 8 x bf16x8 = 32 VGPRs ----
    bf16x8 qf00 = *(const bf16x8*)(qs + m31 * kKP +  0 + 8 * h);
    bf16x8 qf01 = *(const bf16x8*)(qs + m31 * kKP + 16 + 8 * h);
    bf16x8 qf02 = *(const bf16x8*)(qs + m31 * kKP + 32 + 8 * h);
    bf16x8 qf03 = *(const bf16x8*)(qs + m31 * kKP + 48 + 8 * h);
    bf16x8 qf10 = *(const bf16x8*)(qs + (32 + m31) * kKP +  0 + 8 * h);
    bf16x8 qf11 = *(const bf16x8*)(qs + (32 + m31) * kKP + 16 + 8 * h);
    bf16x8 qf12 = *(const bf16x8*)(qs + (32 + m31) * kKP + 32 + 8 * h);
    bf16x8 qf13 = *(const bf16x8*)(qs + (32 + m31) * kKP + 48 + 8 * h);

    // O^T accumulators; l partials per q-half
    f32x16 Oa00, Oa10, Oa01, Oa11;
    #pragma unroll
    for (int r = 0; r < 16; ++r) { Oa00[r] = 0.f; Oa10[r] = 0.f; Oa01[r] = 0.f; Oa11[r] = 0.f; }
    float lacc0 = 0.f, lacc1 = 0.f;

    // ---- single-buffered zero-LDS main loop ----
    bf16x8 k0, k1, k2, k3, v0, v1, v2, v3;
    int jt = wave;
    if (jt <= mtk) {
      const bf16_t* kp = kfb + (size_t)jt * 2048;
      k0 = *(const bf16x8*)(kp);      k1 = *(const bf16x8*)(kp + 16);
      k2 = *(const bf16x8*)(kp + 32); k3 = *(const bf16x8*)(kp + 48);
      const bf16_t* vp = vfb + (size_t)jt * 2048;
      v0 = *(const bf16x8*)(vp);      v1 = *(const bf16x8*)(vp + 8);
      v2 = *(const bf16x8*)(vp + 16); v3 = *(const bf16x8*)(vp + 24);
    }
    for (; jt <= mtk; jt += 8) {
      const int kv0  = jt * 32;
      const bool do0 = (kv0 <= m0);   // half0 live unless tile above diagonal

      // --- QK^T for both q-halves (K frags die here) ---
      f32x16 c0, c1;
      if (do0) {
        #pragma unroll
        for (int r = 0; r < 16; ++r) c0[r] = 0.f;
        c0 = __builtin_amdgcn_mfma_f32_32x32x16_bf16(k0, qf00, c0, 0, 0, 0);
        c0 = __builtin_amdgcn_mfma_f32_32x32x16_bf16(k1, qf01, c0, 0, 0, 0);
        c0 = __builtin_amdgcn_mfma_f32_32x32x16_bf16(k2, qf02, c0, 0, 0, 0);
        c0 = __builtin_amdgcn_mfma_f32_32x32x16_bf16(k3, qf03, c0, 0, 0, 0);
      }
      #pragma unroll
      for (int r = 0; r < 16; ++r) c1[r] = 0.f;
      c1 = __builtin_amdgcn_mfma_f32_32x32x16_bf16(k0, qf10, c1, 0, 0, 0);
      c1 = __builtin_amdgcn_mfma_f32_32x32x16_bf16(k1, qf11, c1, 0, 0, 0);
      c1 = __builtin_amdgcn_mfma_f32_32x32x16_bf16(k2, qf12, c1, 0, 0, 0);
      c1 = __builtin_amdgcn_mfma_f32_32x32x16_bf16(k3, qf13, c1, 0, 0, 0);

      // --- prefetch next K into the same regs (covers softmax+PV below) ---
      if (jt + 8 <= mtk) {
        const bf16_t* kp = kfb + (size_t)(jt + 8) * 2048;
        k0 = *(const bf16x8*)(kp);      k1 = *(const bf16x8*)(kp + 16);
        k2 = *(const bf16x8*)(kp + 32); k3 = *(const bf16x8*)(kp + 48);
      }

      // --- q-half 0: softmax + PV ---
      if (do0) {
        float p[16];
        if (kv0 == m0) {   // diagonal subtile
          #pragma unroll
          for (int r = 0; r < 16; ++r) {
            const int kr = (r & 3) + 8 * (r >> 2) + 4 * h;
            const float e = __builtin_amdgcn_exp2f(c0[r]);
            p[r] = (kr <= m31) ? e : 0.f;
            lacc0 += p[r];
          }
        } else {
          #pragma unroll
          for (int r = 0; r < 16; ++r) { p[r] = __builtin_amdgcn_exp2f(c0[r]); lacc0 += p[r]; }
        }
        bf16x8 pb0, pb1;
        #pragma unroll
        for (int j = 0; j < 8; ++j) { pb0[j] = (bf16_t)p[j]; pb1[j] = (bf16_t)p[8 + j]; }
        Oa00 = __builtin_amdgcn_mfma_f32_32x32x16_bf16(v0, pb0, Oa00, 0, 0, 0);
        Oa10 = __builtin_amdgcn_mfma_f32_32x32x16_bf16(v2, pb0, Oa10, 0, 0, 0);
        Oa00 = __builtin_amdgcn_mfma_f32_32x32x16_bf16(v1, pb1, Oa00, 0, 0, 0);
        Oa10 = __builtin_amdgcn_mfma_f32_32x32x16_bf16(v3, pb1, Oa10, 0, 0, 0);
      }

      // --- q-half 1: softmax + PV (V frags die here) ---
      {
        float p[16];
        if (kv0 == m0 + 32) {   // diagonal subtile
          #pragma unroll
          for (int r = 0; r < 16; ++r) {
            const int kr = (r & 3) + 8 * (r >> 2) + 4 * h;
            const float e = __builtin_amdgcn_exp2f(c1[r]);
            p[r] = (kr <= m31) ? e : 0.f;
            lacc1 += p[r];
          }
        } else {
          #pragma unroll
          for (int r = 0; r < 16; ++r) { p[r] = __builtin_amdgcn_exp2f(c1[r]); lacc1 += p[r]; }
        }
        bf16x8 pb0, pb1;
        #pragma unroll
        for (int j = 0; j < 8; ++j) { pb0[j] = (bf16_t)p[j]; pb1[j] = (bf16_t)p[8 + j]; }
        Oa01 = __builtin_amdgcn_mfma_f32_32x32x16_bf16(v0, pb0, Oa01, 0, 0, 0);
        Oa11 = __builtin_amdgcn_mfma_f32_32x32x16_bf16(v2, pb0, Oa11, 0, 0, 0);
        Oa01 = __builtin_amdgcn_mfma_f32_32x32x16_bf16(v1, pb1, Oa01, 0, 0, 0);
        Oa11 = __builtin_amdgcn_mfma_f32_32x32x16_bf16(v3, pb1, Oa11, 0, 0, 0);
      }

      // --- prefetch next V into the same regs (covers next tile's QK^T) ---
      if (jt + 8 <= mtk) {
        const bf16_t* vp = vfb + (size_t)(jt + 8) * 2048;
        v0 = *(const bf16x8*)(vp);      v1 = *(const bf16x8*)(vp + 8);
        v2 = *(const bf16x8*)(vp + 16); v3 = *(const bf16x8*)(vp + 24);
      }
    }

    // ---- epilogue: two passes (one per q-half), 8-way additive merge via LDS ----
    float* fv   = (float*)smraw;
    float* Om   = fv + wave * 32 * kOmPitch;   // per-wave 32 rows x 68
    float* larr = fv + 8 * 32 * kOmPitch;      // 8 waves x 64 l-partials

    #pragma unroll
    for (int qh = 0; qh < 2; ++qh) {
      __syncthreads();   // pass0: main-loop LDS dead; pass1: pass0 reads done
      {
        const f32x16& A0 = qh ? Oa01 : Oa00;   // d 0..31
        const f32x16& A1 = qh ? Oa11 : Oa10;   // d 32..63
        #pragma unroll
        for (int q = 0; q < 4; ++q) {
          f32x4 w0, w1;
          #pragma unroll
          for (int e = 0; e < 4; ++e) { w0[e] = A0[4 * q + e]; w1[e] = A1[4 * q + e]; }
          *(f32x4*)(Om + (size_t)m31 * kOmPitch + 8 * q + 4 * h)      = w0;
          *(f32x4*)(Om + (size_t)m31 * kOmPitch + 32 + 8 * q + 4 * h) = w1;
        }
        larr[wave * 64 + lane] = qh ? lacc1 : lacc0;
      }
      __syncthreads();
      {
        const int row = tid >> 4;             // 512 float4s: 32 rows x 16 cols
        const int c4  = (tid & 15) * 4;
        float l = 0.f;
        #pragma unroll
        for (int w = 0; w < 8; ++w)
          l += larr[w * 64 + row] + larr[w * 64 + 32 + row];
        const float inv = 1.f / l;
        f32x4 o;
        #pragma unroll
        for (int e = 0; e < 4; ++e) o[e] = 0.f;
        #pragma unroll
        for (int w = 0; w < 8; ++w) {
          const f32x4 a = *(const f32x4*)(fv + w * 32 * kOmPitch + (size_t)row * kOmPitch + c4);
          #pragma unroll
          for (int e = 0; e < 4; ++e) o[e] += a[e];
        }
        #pragma unroll
        for (int e = 0; e < 4; ++e) o[e] *= inv;
        *(f32x4*)(Og + (size_t)(m0 + 32 * qh + row) * kHID + head * kHD + c4) = o;
      }
    }
  }
}

extern "C" void kernel_launch(void* const* d_in, const int* in_sizes, int n_in,
                              void* d_out, int out_size, void* d_ws, size_t ws_size,
                              hipStream_t stream) {
  (void)in_sizes; (void)n_in; (void)ws_size; (void)out_size;
  const float* Q = (const float*)d_in[0];
  const float* K = (const float*)d_in[1];
  const float* V = (const float*)d_in[2];
  float* O = (float*)d_out;
  bf16_t* Kb = (bf16_t*)d_ws;            // 4 MB: [head][t][d] bf16
  bf16_t* Vb = Kb + kKbElems;            // 4 MB: pre-gathered kappa order
  hipLaunchKernelGGL(prep_kernel, dim3(2048), dim3(256), 0, stream, K, V, Kb, Vb);
  dim3 grid(256);    // 16 heads x 16 q-tile PAIRS (31-ip, ip)
  dim3 block(512);   // 8 waves; zero-LDS single-buffer main loop
  hipLaunchKernelGGL(fattn_kernel, grid, block, 0, stream, Q, Kb, Vb, O);
}